// Round 12
// baseline (180.168 us; speedup 1.0000x reference)
//
#include <hip/hip_runtime.h>
#include <math.h>

// Problem constants
#define TT   4096
#define NBB  32
#define NUU  64
#define NHH  256
#define HH   128
#define NYY  64
// Chunking: 512 chunks of 8 steps; carry: 64 groups of 8 (3-level)
#define LCH  8
#define CCH  512
#define NGRP 64

#define PI_HALF 1.5707963267948966f

typedef float  f32x16 __attribute__((ext_vector_type(16)));
typedef __bf16 bf16x8 __attribute__((ext_vector_type(8)));
typedef __bf16 bf16x2 __attribute__((ext_vector_type(2)));
typedef unsigned int uint4v __attribute__((ext_vector_type(4)));

// MFMA 32x32 C/D layout: row = (r&3) + 8*(r>>2) + 4*(lane>>5), col = lane&31
__device__ inline int crow(int r, int lane) { return (r & 3) + 8 * (r >> 2) + 4 * (lane >> 5); }
__device__ inline bf16x8 ldfrag(const unsigned short* p) {
    return __builtin_bit_cast(bf16x8, *(const uint4v*)p);
}

// split a float into bf16 hi + bf16 lo (hi+lo ~ exact to 2^-17 rel)
#define CVT(v, H, L) { __bf16 _h = (__bf16)(v); H = _h; L = (__bf16)((v) - (float)_h); }

// lambda in fp32 with correctly-rounded transcendentals (double -> fp32)
__device__ inline void lam_f32(float xre, float xim, float& lr, float& li) {
    float th = PI_HALF * xim;
    float rf = (float)exp(-(double)fabsf(xre));
    float cf = (float)cos((double)th);
    float sf = (float)sin((double)th);
    lr = rf * cf; li = rf * sf;
}

// --- swizzled LDS index helpers (offsets in shorts) -----------------------
// pass2 sU (64 rows x 128): 16B chunk ^= row&15
__device__ inline int swzU(int row, int so) {
    return row * 128 + ((((so >> 3) ^ row) & 15) << 3) + (so & 7);
}
// pass2 sX (64 rows x 512): low-5 of chunk ^= row, bit5 kept
__device__ inline int swzX(int row, int so) {
    int chv = so >> 3;
    chv = (chv & 32) | ((chv ^ row) & 31);
    return row * 512 + (chv << 3) + (so & 7);
}

// ---------------------------------------------------------------------------
// Prep (grid 161):
//  bx 0..31   : x0 pairs
//  bx 32..95  : split B (plain, for pass2) and W_x2y (interleaved K permute)
//  bx 96..159 : B'' tables for pass1-GEMM (lane-coalesced fragment order)
//  bx 160     : lambda^8 f64 table (128 channels)
// ---------------------------------------------------------------------------
__global__ __launch_bounds__(256) void k_prep(
    const float* __restrict__ B, const float* __restrict__ W,
    const float* __restrict__ y0, const float* __restrict__ Wy2x,
    const float* __restrict__ by2x,
    const float* __restrict__ lre, const float* __restrict__ lim,
    unsigned short* __restrict__ Bph, unsigned short* __restrict__ Bpl,
    unsigned short* __restrict__ Wph, unsigned short* __restrict__ Wpl,
    unsigned short* __restrict__ Bq2h, unsigned short* __restrict__ Bq2l,
    double2* __restrict__ lam8tab, float2* __restrict__ x0p)
{
    int bx = blockIdx.x, tid = threadIdx.x;
    if (bx < 32) {
        if (tid < HH) {
            int b = bx, ch = tid;
            float xr = by2x[ch], xi = by2x[ch + HH];
            for (int y = 0; y < NYY; ++y) {
                float v = y0[b * NYY + y];
                xr += v * Wy2x[ch * NYY + y];
                xi += v * Wy2x[(ch + HH) * NYY + y];
            }
            x0p[b * HH + ch] = make_float2(xr, xi);
        }
    } else if (bx < 96) {
        int i = (bx - 32) * 256 + tid;            // 0..16383
        float bv = B[i];
        __bf16 bh = (__bf16)bv;
        Bph[i] = __builtin_bit_cast(unsigned short, bh);
        Bpl[i] = __builtin_bit_cast(unsigned short, (__bf16)(bv - (float)bh));
        int y = i >> 8, kidx = i & 255;
        float wv = W[y * NHH + (kidx & 1) * HH + (kidx >> 1)];
        __bf16 wh = (__bf16)wv;
        Wph[i] = __builtin_bit_cast(unsigned short, wh);
        Wpl[i] = __builtin_bit_cast(unsigned short, (__bf16)(wv - (float)wh));
    } else if (bx < 160) {
        int F = (bx - 96) * 256 + tid;            // fragment id, 0..16383
        int lane = F & 63, kk = (F >> 6) & 31, w = (F >> 11) & 3, nt = (F >> 13) & 1;
        int l31 = lane & 31, kh = lane >> 5;
        int ch = w * 32 + l31;
        int kb = kk * 16 + kh * 8;                // K base; j constant over e
        int j = kb >> 6;
        float lrf, lif; lam_f32(lre[ch], lim[ch], lrf, lif);
        double pr = 1.0, pi_ = 0.0;
        for (int s = 0; s < 7 - j; ++s) {
            double nr = pr * (double)lrf - pi_ * (double)lif;
            double ni = pr * (double)lif + pi_ * (double)lrf;
            pr = nr; pi_ = ni;
        }
        for (int e = 0; e < 8; ++e) {
            int u = (kb + e) & 63;
            double b0 = (double)B[ch * NUU + u];
            double b1 = (double)B[(ch + HH) * NUU + u];
            float val = (nt == 0) ? (float)(pr * b0 - pi_ * b1)
                                  : (float)(pi_ * b0 + pr * b1);
            __bf16 vh = (__bf16)val;
            Bq2h[(size_t)F * 8 + e] = __builtin_bit_cast(unsigned short, vh);
            Bq2l[(size_t)F * 8 + e] = __builtin_bit_cast(unsigned short, (__bf16)(val - (float)vh));
        }
    } else {
        if (tid < HH) {
            float lrf, lif; lam_f32(lre[tid], lim[tid], lrf, lif);
            double pr = (double)lrf, pi_ = (double)lif;
#pragma unroll
            for (int s = 0; s < 3; ++s) { double nr = pr*pr - pi_*pi_, ni = 2.0*pr*pi_; pr = nr; pi_ = ni; } // lambda^8
            lam8tab[tid] = make_double2(pr, pi_);
        }
    }
}

// ---------------------------------------------------------------------------
// Pass 1: pure GEMM (R11, verbatim). E[c] = U_tile(32x512) @ B''^T.
// ---------------------------------------------------------------------------
__global__ __launch_bounds__(256, 1) void k_pass1(
    const float* __restrict__ U,
    const unsigned short* __restrict__ Bq2h, const unsigned short* __restrict__ Bq2l,
    float2* __restrict__ E)
{
    __shared__ __align__(16) unsigned short sL[32 * 1024];   // 65536 B

    const int tid = threadIdx.x, w = tid >> 6, lane = tid & 63;
    const int l31 = lane & 31, kh = lane >> 5;
    const int c = blockIdx.x;
    const int ch = w * 32 + l31;

    // stage U tile: 16384 floats, 4 rounds x 16 floats/thread, swizzled write
#pragma unroll
    for (int p = 0; p < 4; ++p) {
        int flat0 = p * 4096 + tid * 16;
        const float4* sp = (const float4*)(U + (size_t)c * 16384 + flat0);
        float4 f0 = sp[0], f1 = sp[1], f2 = sp[2], f3 = sp[3];
        int j = flat0 >> 11, b = (flat0 >> 6) & 31, u0 = flat0 & 63;
        bf16x8 h0, h1, l0, l1;
        CVT(f0.x, h0[0], l0[0]); CVT(f0.y, h0[1], l0[1]); CVT(f0.z, h0[2], l0[2]); CVT(f0.w, h0[3], l0[3]);
        CVT(f1.x, h0[4], l0[4]); CVT(f1.y, h0[5], l0[5]); CVT(f1.z, h0[6], l0[6]); CVT(f1.w, h0[7], l0[7]);
        CVT(f2.x, h1[0], l1[0]); CVT(f2.y, h1[1], l1[1]); CVT(f2.z, h1[2], l1[2]); CVT(f2.w, h1[3], l1[3]);
        CVT(f3.x, h1[4], l1[4]); CVT(f3.y, h1[5], l1[5]); CVT(f3.z, h1[6], l1[6]); CVT(f3.w, h1[7], l1[7]);
        int m  = b & 15;
        int cA = ((j * 8 + (u0 >> 3))     ^ m);
        int cB = ((j * 8 + (u0 >> 3) + 1) ^ m);
        *(bf16x8*)&sL[b * 1024 + cA * 8]       = h0;
        *(bf16x8*)&sL[b * 1024 + cB * 8]       = h1;
        *(bf16x8*)&sL[b * 1024 + 512 + cA * 8] = l0;
        *(bf16x8*)&sL[b * 1024 + 512 + cB * 8] = l1;
    }
    __syncthreads();

    // B'' bases for this wave (lane-coalesced: +lane*8, stride 512/kk)
    const unsigned short* b0h = Bq2h + ((size_t)(0 + w) * 32) * 512 + lane * 8;
    const unsigned short* b1h = Bq2h + ((size_t)(4 + w) * 32) * 512 + lane * 8;
    const unsigned short* b0l = Bq2l + ((size_t)(0 + w) * 32) * 512 + lane * 8;
    const unsigned short* b1l = Bq2l + ((size_t)(4 + w) * 32) * 512 + lane * 8;

    f32x16 acc0, acc1;
#pragma unroll
    for (int r = 0; r < 16; ++r) { acc0[r] = 0.f; acc1[r] = 0.f; }

    const int m = l31 & 15;
    const int rowb = l31 * 1024;
#pragma unroll 4
    for (int kk = 0; kk < 32; ++kk) {
        int chs = ((kk * 2 + kh) ^ m) * 8;
        bf16x8 ah  = ldfrag(&sL[rowb + chs]);
        bf16x8 al  = ldfrag(&sL[rowb + 512 + chs]);
        bf16x8 bh0 = ldfrag(b0h + (size_t)kk * 512);
        bf16x8 bh1 = ldfrag(b1h + (size_t)kk * 512);
        bf16x8 bl0 = ldfrag(b0l + (size_t)kk * 512);
        bf16x8 bl1 = ldfrag(b1l + (size_t)kk * 512);
        acc0 = __builtin_amdgcn_mfma_f32_32x32x16_bf16(ah, bh0, acc0, 0, 0, 0);
        acc1 = __builtin_amdgcn_mfma_f32_32x32x16_bf16(ah, bh1, acc1, 0, 0, 0);
        acc0 = __builtin_amdgcn_mfma_f32_32x32x16_bf16(al, bh0, acc0, 0, 0, 0);
        acc1 = __builtin_amdgcn_mfma_f32_32x32x16_bf16(al, bh1, acc1, 0, 0, 0);
        acc0 = __builtin_amdgcn_mfma_f32_32x32x16_bf16(ah, bl0, acc0, 0, 0, 0);
        acc1 = __builtin_amdgcn_mfma_f32_32x32x16_bf16(ah, bl1, acc1, 0, 0, 0);
    }

#pragma unroll
    for (int r = 0; r < 16; ++r)
        E[(size_t)c * 4096 + crow(r, lane) * HH + ch] = make_float2(acc0[r], acc1[r]);
}

// ---------------------------------------------------------------------------
// 3-level carry hierarchy (v12). chain = b*128 + ch, 4096 chains.
// A: G[g] = sum_{j=0..7} lam8^{7-j} E[8g+j]   (262K threads)
// B: GC[g] = carry before group g (lam64 chain over G, loads hoisted)
// C: Carry[c] = GC[c>>3] advanced (c&7) chunk-steps  (2M threads, <=7 steps)
// ---------------------------------------------------------------------------
__global__ __launch_bounds__(256) void k_cA(
    const double2* __restrict__ lam8tab,
    const float2* __restrict__ E, float2* __restrict__ G)
{
    int g = blockIdx.x * 256 + threadIdx.x;      // 0..262143
    int chain = g & 4095, grp = g >> 12;         // grp 0..63
    double2 l8 = lam8tab[chain & 127];
    float2 e[8];
#pragma unroll
    for (int j = 0; j < 8; ++j)
        e[j] = E[((size_t)grp * 8 + j) * 4096 + chain];
    double sr = 0.0, si = 0.0;
#pragma unroll
    for (int j = 0; j < 8; ++j) {
        double nr = l8.x * sr - l8.y * si + (double)e[j].x;
        double ni = l8.y * sr + l8.x * si + (double)e[j].y;
        sr = nr; si = ni;
    }
    G[(size_t)grp * 4096 + chain] = make_float2((float)sr, (float)si);
}

__global__ __launch_bounds__(256) void k_cB(
    const double2* __restrict__ lam8tab,
    const float2* __restrict__ x0p, const float2* __restrict__ G,
    float2* __restrict__ GC)
{
    int chain = blockIdx.x * 256 + threadIdx.x;  // grid 16 -> 0..4095
    double2 l8 = lam8tab[chain & 127];
    double pr = l8.x, pi = l8.y;
#pragma unroll
    for (int s = 0; s < 3; ++s) { double nr = pr*pr - pi*pi, ni = 2.0*pr*pi; pr = nr; pi = ni; } // lambda^64
    float2 gs[NGRP];
#pragma unroll
    for (int g = 0; g < NGRP; ++g)
        gs[g] = G[(size_t)g * 4096 + chain];
    float2 c0 = x0p[chain];
    double cr = (double)c0.x, ci = (double)c0.y;
#pragma unroll
    for (int g = 0; g < NGRP; ++g) {
        GC[(size_t)g * 4096 + chain] = make_float2((float)cr, (float)ci);
        double nr = pr * cr - pi * ci + (double)gs[g].x;
        double ni = pi * cr + pr * ci + (double)gs[g].y;
        cr = nr; ci = ni;
    }
}

__global__ __launch_bounds__(256) void k_cC(
    const double2* __restrict__ lam8tab,
    const float2* __restrict__ GC, const float2* __restrict__ E,
    float2* __restrict__ Carry)
{
    int g = blockIdx.x * 256 + threadIdx.x;      // 0..2097151
    int chain = g & 4095, c = g >> 12;           // c uniform per block
    int grp = c >> 3, o = c & 7;
    double2 l8 = lam8tab[chain & 127];
    float2 gc = GC[(size_t)grp * 4096 + chain];
    double cr = (double)gc.x, ci = (double)gc.y;
    for (int k = 0; k < o; ++k) {
        float2 e = E[((size_t)(grp * 8 + k)) * 4096 + chain];
        double nr = l8.x * cr - l8.y * ci + (double)e.x;
        double ni = l8.y * cr + l8.x * ci + (double)e.y;
        cr = nr; ci = ni;
    }
    Carry[(size_t)c * 4096 + chain] = make_float2((float)cr, (float)ci);
}

// ---------------------------------------------------------------------------
// Pass 2: R2's measured-best kernel, verbatim (53.4 / 53.3 us; do not touch).
// LDS = 16384 (sU swz) + 65536 (sX swz) = 81920 B; (256,1); VGPR 256.
// ---------------------------------------------------------------------------
__global__ __launch_bounds__(256, 1) void k_pass2(
    const float* __restrict__ U,
    const unsigned short* __restrict__ Bph, const unsigned short* __restrict__ Bpl,
    const unsigned short* __restrict__ Wph, const unsigned short* __restrict__ Wpl,
    const float* __restrict__ lre, const float* __restrict__ lim,
    const float* __restrict__ bx2y,
    const float2* __restrict__ Carry, float* __restrict__ Y)
{
    __shared__ __align__(16) unsigned short sU[64 * 128];   // 16384 B, swizzled
    __shared__ __align__(16) unsigned short sX[64 * 512];   // 65536 B, swizzled

    const int tid = threadIdx.x, w = tid >> 6, lane = tid & 63;
    const int l31 = lane & 31, kh = lane >> 5;
    const int c = blockIdx.x;
    const int ch = w * 32 + l31;             // scan channel
    const int mtile = w & 1, ntile = w >> 1; // out-GEMM tile mapping

    float lr, li; lam_f32(lre[ch], lim[ch], lr, li);
    float ybias = bx2y[ntile * 32 + l31];

    bf16x8 bfh[2][4], bfl[2][4];
#pragma unroll
    for (int nt = 0; nt < 2; ++nt)
#pragma unroll
        for (int kk = 0; kk < 4; ++kk) {
            bfh[nt][kk] = ldfrag(&Bph[(size_t)(nt * HH + ch) * NUU + kk * 16 + kh * 8]);
            bfl[nt][kk] = ldfrag(&Bpl[(size_t)(nt * HH + ch) * NUU + kk * 16 + kh * 8]);
        }

    bf16x8 wfh[16], wfl[16];
#pragma unroll
    for (int kk = 0; kk < 16; ++kk) {
        wfh[kk] = ldfrag(&Wph[(size_t)(ntile * 32 + l31) * NHH + kk * 16 + kh * 8]);
        wfl[kk] = ldfrag(&Wpl[(size_t)(ntile * 32 + l31) * NHH + kk * 16 + kh * 8]);
    }

    float zr[16], zi[16];
#pragma unroll
    for (int r = 0; r < 16; ++r) {
        float2 v = Carry[(size_t)c * 4096 + crow(r, lane) * HH + ch];
        zr[r] = v.x; zi[r] = v.y;
    }

    const int srow = tid >> 2, sus = (tid & 3) * 16;
    const int sb = srow & 31, stoff = srow >> 5;
    const float* ubase = U + (size_t)sb * NUU + sus;

    float4 f0, f1, f2, f3;
    {
        const float4* sp = (const float4*)(ubase + (size_t)(c * LCH + stoff) * (NBB * NUU));
        f0 = sp[0]; f1 = sp[1]; f2 = sp[2]; f3 = sp[3];
    }

    for (int sub = 0; sub < 4; ++sub) {
        {   // convert + write sU (swizzled)
            bf16x8 h0, h1, l0, l1;
            CVT(f0.x, h0[0], l0[0]); CVT(f0.y, h0[1], l0[1]); CVT(f0.z, h0[2], l0[2]); CVT(f0.w, h0[3], l0[3]);
            CVT(f1.x, h0[4], l0[4]); CVT(f1.y, h0[5], l0[5]); CVT(f1.z, h0[6], l0[6]); CVT(f1.w, h0[7], l0[7]);
            CVT(f2.x, h1[0], l1[0]); CVT(f2.y, h1[1], l1[1]); CVT(f2.z, h1[2], l1[2]); CVT(f2.w, h1[3], l1[3]);
            CVT(f3.x, h1[4], l1[4]); CVT(f3.y, h1[5], l1[5]); CVT(f3.z, h1[6], l1[6]); CVT(f3.w, h1[7], l1[7]);
            *(bf16x8*)&sU[swzU(srow, sus)]          = h0;
            *(bf16x8*)&sU[swzU(srow, sus + 8)]      = h1;
            *(bf16x8*)&sU[swzU(srow, 64 + sus)]     = l0;
            *(bf16x8*)&sU[swzU(srow, 64 + sus + 8)] = l1;
        }

        if (sub > 0) {  // out-GEMM for sub-1 (reads sX written before last barrier)
            f32x16 ya0, ya1, ya2;
#pragma unroll
            for (int r = 0; r < 16; ++r) { ya0[r] = 0.f; ya1[r] = 0.f; ya2[r] = 0.f; }
#pragma unroll
            for (int kk = 0; kk < 16; ++kk) {
                bf16x8 xah = ldfrag(&sX[swzX(mtile * 32 + l31, kk * 16 + kh * 8)]);
                bf16x8 xal = ldfrag(&sX[swzX(mtile * 32 + l31, 256 + kk * 16 + kh * 8)]);
                ya0 = __builtin_amdgcn_mfma_f32_32x32x16_bf16(xah, wfh[kk], ya0, 0, 0, 0);
                ya1 = __builtin_amdgcn_mfma_f32_32x32x16_bf16(xal, wfh[kk], ya1, 0, 0, 0);
                ya2 = __builtin_amdgcn_mfma_f32_32x32x16_bf16(xah, wfl[kk], ya2, 0, 0, 0);
            }
            int t = c * LCH + (sub - 1) * 2 + mtile;
#pragma unroll
            for (int r = 0; r < 16; ++r)
                Y[((size_t)t * NBB + crow(r, lane)) * NYY + ntile * 32 + l31] =
                    (ya0[r] + ya1[r]) + ya2[r] + ybias;
        }
        __syncthreads();

        if (sub < 3) {   // prefetch next sub; lands under the MFMA phase
            const float4* sp = (const float4*)(ubase + (size_t)(c * LCH + (sub + 1) * 2 + stoff) * (NBB * NUU));
            f0 = sp[0]; f1 = sp[1]; f2 = sp[2]; f3 = sp[3];
        }

        // Bu MFMA (split 3-term)
        f32x16 acc[2][2];
#pragma unroll
        for (int mt = 0; mt < 2; ++mt)
#pragma unroll
            for (int nt = 0; nt < 2; ++nt)
#pragma unroll
                for (int r = 0; r < 16; ++r) acc[mt][nt][r] = 0.f;

#pragma unroll
        for (int kk = 0; kk < 4; ++kk) {
            bf16x8 a0h = ldfrag(&sU[swzU(l31,      kk * 16 + kh * 8)]);
            bf16x8 a1h = ldfrag(&sU[swzU(32 + l31, kk * 16 + kh * 8)]);
            bf16x8 a0l = ldfrag(&sU[swzU(l31,      64 + kk * 16 + kh * 8)]);
            bf16x8 a1l = ldfrag(&sU[swzU(32 + l31, 64 + kk * 16 + kh * 8)]);
            acc[0][0] = __builtin_amdgcn_mfma_f32_32x32x16_bf16(a0h, bfh[0][kk], acc[0][0], 0, 0, 0);
            acc[0][1] = __builtin_amdgcn_mfma_f32_32x32x16_bf16(a0h, bfh[1][kk], acc[0][1], 0, 0, 0);
            acc[1][0] = __builtin_amdgcn_mfma_f32_32x32x16_bf16(a1h, bfh[0][kk], acc[1][0], 0, 0, 0);
            acc[1][1] = __builtin_amdgcn_mfma_f32_32x32x16_bf16(a1h, bfh[1][kk], acc[1][1], 0, 0, 0);
            acc[0][0] = __builtin_amdgcn_mfma_f32_32x32x16_bf16(a0l, bfh[0][kk], acc[0][0], 0, 0, 0);
            acc[0][1] = __builtin_amdgcn_mfma_f32_32x32x16_bf16(a0l, bfh[1][kk], acc[0][1], 0, 0, 0);
            acc[1][0] = __builtin_amdgcn_mfma_f32_32x32x16_bf16(a1l, bfh[0][kk], acc[1][0], 0, 0, 0);
            acc[1][1] = __builtin_amdgcn_mfma_f32_32x32x16_bf16(a1l, bfh[1][kk], acc[1][1], 0, 0, 0);
            acc[0][0] = __builtin_amdgcn_mfma_f32_32x32x16_bf16(a0h, bfl[0][kk], acc[0][0], 0, 0, 0);
            acc[0][1] = __builtin_amdgcn_mfma_f32_32x32x16_bf16(a0h, bfl[1][kk], acc[0][1], 0, 0, 0);
            acc[1][0] = __builtin_amdgcn_mfma_f32_32x32x16_bf16(a1h, bfl[0][kk], acc[1][0], 0, 0, 0);
            acc[1][1] = __builtin_amdgcn_mfma_f32_32x32x16_bf16(a1h, bfl[1][kk], acc[1][1], 0, 0, 0);
        }

        // Scan + split hi/lo dump (two b32 per (mt,r)), swizzled
#pragma unroll
        for (int mt = 0; mt < 2; ++mt)
#pragma unroll
            for (int r = 0; r < 16; ++r) {
                float t0 = fmaf(lr, zr[r], acc[mt][0][r]); t0 = fmaf(-li, zi[r], t0);
                float t1 = fmaf(li, zr[r], acc[mt][1][r]); t1 = fmaf(lr, zi[r], t1);
                zr[r] = t0; zi[r] = t1;
                bf16x2 hv, lv;
                { __bf16 _h = (__bf16)t0; hv[0] = _h; lv[0] = (__bf16)(t0 - (float)_h); }
                { __bf16 _h = (__bf16)t1; hv[1] = _h; lv[1] = (__bf16)(t1 - (float)_h); }
                int row = mt * 32 + crow(r, lane);
                *(bf16x2*)&sX[swzX(row, w * 64 + 2 * l31)]       = hv;
                *(bf16x2*)&sX[swzX(row, 256 + w * 64 + 2 * l31)] = lv;
            }
        __syncthreads();
    }

    // Drain: out-GEMM for sub=3
    {
        f32x16 ya0, ya1, ya2;
#pragma unroll
        for (int r = 0; r < 16; ++r) { ya0[r] = 0.f; ya1[r] = 0.f; ya2[r] = 0.f; }
#pragma unroll
        for (int kk = 0; kk < 16; ++kk) {
            bf16x8 xah = ldfrag(&sX[swzX(mtile * 32 + l31, kk * 16 + kh * 8)]);
            bf16x8 xal = ldfrag(&sX[swzX(mtile * 32 + l31, 256 + kk * 16 + kh * 8)]);
            ya0 = __builtin_amdgcn_mfma_f32_32x32x16_bf16(xah, wfh[kk], ya0, 0, 0, 0);
            ya1 = __builtin_amdgcn_mfma_f32_32x32x16_bf16(xal, wfh[kk], ya1, 0, 0, 0);
            ya2 = __builtin_amdgcn_mfma_f32_32x32x16_bf16(xah, wfl[kk], ya2, 0, 0, 0);
        }
        int t = c * LCH + 3 * 2 + mtile;
#pragma unroll
        for (int r = 0; r < 16; ++r)
            Y[((size_t)t * NBB + crow(r, lane)) * NYY + ntile * 32 + l31] =
                (ya0[r] + ya1[r]) + ya2[r] + ybias;
    }
}

// ---------------------------------------------------------------------------
extern "C" void kernel_launch(void* const* d_in, const int* in_sizes, int n_in,
                              void* d_out, int out_size, void* d_ws, size_t ws_size,
                              hipStream_t stream) {
    const float* y0    = (const float*)d_in[0];
    const float* U     = (const float*)d_in[1];
    const float* lre   = (const float*)d_in[2];
    const float* lim   = (const float*)d_in[3];
    const float* B     = (const float*)d_in[4];
    const float* W_y2x = (const float*)d_in[5];
    const float* b_y2x = (const float*)d_in[6];
    const float* W_x2y = (const float*)d_in[7];
    const float* b_x2y = (const float*)d_in[8];
    float* Y = (float*)d_out;

    char* p = (char*)d_ws;
    float2* E        = (float2*)p; p += (size_t)CCH * 4096 * sizeof(float2);   // 16.8 MB
    float2* Carry    = (float2*)p; p += (size_t)CCH * 4096 * sizeof(float2);   // 16.8 MB
    float2* G        = (float2*)p; p += (size_t)NGRP * 4096 * sizeof(float2);  // 2 MB
    float2* GC       = (float2*)p; p += (size_t)NGRP * 4096 * sizeof(float2);  // 2 MB
    float2* x0p      = (float2*)p; p += (size_t)4096 * sizeof(float2);         // 32 KB
    double2* lam8tab = (double2*)p; p += (size_t)HH * sizeof(double2);         // 2 KB
    unsigned short* Bph  = (unsigned short*)p; p += 16384 * sizeof(unsigned short);
    unsigned short* Bpl  = (unsigned short*)p; p += 16384 * sizeof(unsigned short);
    unsigned short* Wph  = (unsigned short*)p; p += 16384 * sizeof(unsigned short);
    unsigned short* Wpl  = (unsigned short*)p; p += 16384 * sizeof(unsigned short);
    unsigned short* Bq2h = (unsigned short*)p; p += 131072 * sizeof(unsigned short); // 256 KB
    unsigned short* Bq2l = (unsigned short*)p; p += 131072 * sizeof(unsigned short); // 256 KB

    k_prep <<<dim3(161), dim3(256), 0, stream>>>(B, W_x2y, y0, W_y2x, b_y2x,
                                                 lre, lim,
                                                 Bph, Bpl, Wph, Wpl,
                                                 Bq2h, Bq2l, lam8tab, x0p);
    k_pass1<<<dim3(CCH),  dim3(256), 0, stream>>>(U, Bq2h, Bq2l, E);
    k_cA   <<<dim3(1024), dim3(256), 0, stream>>>(lam8tab, E, G);
    k_cB   <<<dim3(16),   dim3(256), 0, stream>>>(lam8tab, x0p, G, GC);
    k_cC   <<<dim3(8192), dim3(256), 0, stream>>>(lam8tab, GC, E, Carry);
    k_pass2<<<dim3(CCH),  dim3(256), 0, stream>>>(U, Bph, Bpl, Wph, Wpl, lre, lim, b_x2y, Carry, Y);
}

// Round 13
// 170.570 us; speedup vs baseline: 1.0563x; 1.0563x over previous
//
#include <hip/hip_runtime.h>
#include <math.h>

// Problem constants
#define TT   4096
#define NBB  32
#define NUU  64
#define NHH  256
#define HH   128
#define NYY  64
// Chunking: 512 chunks of 8 steps; carry hierarchy: 16 supers x 32 chunks
#define LCH  8
#define CCH  512
#define SEGN 16
#define CPS  32

#define PI_HALF 1.5707963267948966f

typedef float  f32x16 __attribute__((ext_vector_type(16)));
typedef __bf16 bf16x8 __attribute__((ext_vector_type(8)));
typedef __bf16 bf16x2 __attribute__((ext_vector_type(2)));
typedef unsigned int uint4v __attribute__((ext_vector_type(4)));

// MFMA 32x32 C/D layout: row = (r&3) + 8*(r>>2) + 4*(lane>>5), col = lane&31
__device__ inline int crow(int r, int lane) { return (r & 3) + 8 * (r >> 2) + 4 * (lane >> 5); }
__device__ inline bf16x8 ldfrag(const unsigned short* p) {
    return __builtin_bit_cast(bf16x8, *(const uint4v*)p);
}

// split a float into bf16 hi + bf16 lo (hi+lo ~ exact to 2^-17 rel)
#define CVT(v, H, L) { __bf16 _h = (__bf16)(v); H = _h; L = (__bf16)((v) - (float)_h); }

// lambda in fp32 with correctly-rounded transcendentals (double -> fp32)
__device__ inline void lam_f32(float xre, float xim, float& lr, float& li) {
    float th = PI_HALF * xim;
    float rf = (float)exp(-(double)fabsf(xre));
    float cf = (float)cos((double)th);
    float sf = (float)sin((double)th);
    lr = rf * cf; li = rf * sf;
}

// --- swizzled LDS index helpers for pass2 (offsets in shorts) -------------
// pass2 sU (64 rows x 128): 16B chunk ^= row&15
__device__ inline int swzU(int row, int so) {
    return row * 128 + ((((so >> 3) ^ row) & 15) << 3) + (so & 7);
}
// pass2 sX (64 rows x 512): low-5 of chunk ^= row, bit5 kept
__device__ inline int swzX(int row, int so) {
    int chv = so >> 3;
    chv = (chv & 32) | ((chv ^ row) & 31);
    return row * 512 + (chv << 3) + (so & 7);
}

// ---------------------------------------------------------------------------
// Prep: x0 pairs; bf16 hi/lo split of B (plain) and W_x2y with interleaved K
// permute: Wp[y][2j] = W[y][j], Wp[y][2j+1] = W[y][j+128].
// ---------------------------------------------------------------------------
__global__ __launch_bounds__(256) void k_prep(
    const float* __restrict__ B, const float* __restrict__ W,
    const float* __restrict__ y0, const float* __restrict__ Wy2x,
    const float* __restrict__ by2x,
    unsigned short* __restrict__ Bph, unsigned short* __restrict__ Bpl,
    unsigned short* __restrict__ Wph, unsigned short* __restrict__ Wpl,
    float2* __restrict__ x0p)
{
    int bx = blockIdx.x, tid = threadIdx.x;
    if (bx < 32) {
        if (tid < HH) {
            int b = bx, ch = tid;
            float xr = by2x[ch], xi = by2x[ch + HH];
            for (int y = 0; y < NYY; ++y) {
                float v = y0[b * NYY + y];
                xr += v * Wy2x[ch * NYY + y];
                xi += v * Wy2x[(ch + HH) * NYY + y];
            }
            x0p[b * HH + ch] = make_float2(xr, xi);
        }
    } else {
        int i = (bx - 32) * 256 + tid;            // 0..16383
        float bv = B[i];
        __bf16 bh = (__bf16)bv;
        Bph[i] = __builtin_bit_cast(unsigned short, bh);
        Bpl[i] = __builtin_bit_cast(unsigned short, (__bf16)(bv - (float)bh));
        int y = i >> 8, kidx = i & 255;
        float wv = W[y * NHH + (kidx & 1) * HH + (kidx >> 1)];
        __bf16 wh = (__bf16)wv;
        Wph[i] = __builtin_bit_cast(unsigned short, wh);
        Wpl[i] = __builtin_bit_cast(unsigned short, (__bf16)(wv - (float)wh));
    }
}

// ---------------------------------------------------------------------------
// Pass 1: R2's exact proven kernel (R9 record build, verbatim).
// ---------------------------------------------------------------------------
__global__ __launch_bounds__(256, 1) void k_pass1(
    const float* __restrict__ U,
    const unsigned short* __restrict__ Bph, const unsigned short* __restrict__ Bpl,
    const float* __restrict__ lre, const float* __restrict__ lim,
    float2* __restrict__ E)
{
    __shared__ __align__(16) unsigned short sU[2][64 * 136];   // 2 x 17.4 KB

    const int tid = threadIdx.x, w = tid >> 6, lane = tid & 63;
    const int l31 = lane & 31, kh = lane >> 5;
    const int c = blockIdx.x;
    const int ch = w * 32 + l31;

    float lr, li; lam_f32(lre[ch], lim[ch], lr, li);

    bf16x8 bfh[2][4], bfl[2][4];
#pragma unroll
    for (int nt = 0; nt < 2; ++nt)
#pragma unroll
        for (int kk = 0; kk < 4; ++kk) {
            bfh[nt][kk] = ldfrag(&Bph[(size_t)(nt * HH + ch) * NUU + kk * 16 + kh * 8]);
            bfl[nt][kk] = ldfrag(&Bpl[(size_t)(nt * HH + ch) * NUU + kk * 16 + kh * 8]);
        }

    float zr[16], zi[16];
#pragma unroll
    for (int r = 0; r < 16; ++r) { zr[r] = 0.f; zi[r] = 0.f; }

    const int srow = tid >> 2, sus = (tid & 3) * 16;
    const int sb = srow & 31, stoff = srow >> 5;
    const float* ubase = U + (size_t)sb * NUU + sus;

    float4 f0, f1, f2, f3;
    {
        const float4* sp = (const float4*)(ubase + (size_t)(c * LCH + stoff) * (NBB * NUU));
        f0 = sp[0]; f1 = sp[1]; f2 = sp[2]; f3 = sp[3];
    }

    for (int sub = 0; sub < 4; ++sub) {
        unsigned short* su = &sU[sub & 1][0];
        {   // convert staged regs -> split-bf16, write LDS
            bf16x8 h0, h1, l0, l1;
            CVT(f0.x, h0[0], l0[0]); CVT(f0.y, h0[1], l0[1]); CVT(f0.z, h0[2], l0[2]); CVT(f0.w, h0[3], l0[3]);
            CVT(f1.x, h0[4], l0[4]); CVT(f1.y, h0[5], l0[5]); CVT(f1.z, h0[6], l0[6]); CVT(f1.w, h0[7], l0[7]);
            CVT(f2.x, h1[0], l1[0]); CVT(f2.y, h1[1], l1[1]); CVT(f2.z, h1[2], l1[2]); CVT(f2.w, h1[3], l1[3]);
            CVT(f3.x, h1[4], l1[4]); CVT(f3.y, h1[5], l1[5]); CVT(f3.z, h1[6], l1[6]); CVT(f3.w, h1[7], l1[7]);
            *(bf16x8*)&su[srow * 136 + sus]          = h0;
            *(bf16x8*)&su[srow * 136 + sus + 8]      = h1;
            *(bf16x8*)&su[srow * 136 + 64 + sus]     = l0;
            *(bf16x8*)&su[srow * 136 + 64 + sus + 8] = l1;
        }
        __syncthreads();

        if (sub < 3) {   // prefetch next sub while MFMA runs
            const float4* sp = (const float4*)(ubase + (size_t)(c * LCH + (sub + 1) * 2 + stoff) * (NBB * NUU));
            f0 = sp[0]; f1 = sp[1]; f2 = sp[2]; f3 = sp[3];
        }

        f32x16 acc[2][2];
#pragma unroll
        for (int mt = 0; mt < 2; ++mt)
#pragma unroll
            for (int nt = 0; nt < 2; ++nt)
#pragma unroll
                for (int r = 0; r < 16; ++r) acc[mt][nt][r] = 0.f;

#pragma unroll
        for (int kk = 0; kk < 4; ++kk) {
            bf16x8 a0h = ldfrag(&su[(l31)      * 136 + kk * 16 + kh * 8]);
            bf16x8 a1h = ldfrag(&su[(32 + l31) * 136 + kk * 16 + kh * 8]);
            bf16x8 a0l = ldfrag(&su[(l31)      * 136 + 64 + kk * 16 + kh * 8]);
            bf16x8 a1l = ldfrag(&su[(32 + l31) * 136 + 64 + kk * 16 + kh * 8]);
            acc[0][0] = __builtin_amdgcn_mfma_f32_32x32x16_bf16(a0h, bfh[0][kk], acc[0][0], 0, 0, 0);
            acc[0][1] = __builtin_amdgcn_mfma_f32_32x32x16_bf16(a0h, bfh[1][kk], acc[0][1], 0, 0, 0);
            acc[1][0] = __builtin_amdgcn_mfma_f32_32x32x16_bf16(a1h, bfh[0][kk], acc[1][0], 0, 0, 0);
            acc[1][1] = __builtin_amdgcn_mfma_f32_32x32x16_bf16(a1h, bfh[1][kk], acc[1][1], 0, 0, 0);
            acc[0][0] = __builtin_amdgcn_mfma_f32_32x32x16_bf16(a0l, bfh[0][kk], acc[0][0], 0, 0, 0);
            acc[0][1] = __builtin_amdgcn_mfma_f32_32x32x16_bf16(a0l, bfh[1][kk], acc[0][1], 0, 0, 0);
            acc[1][0] = __builtin_amdgcn_mfma_f32_32x32x16_bf16(a1l, bfh[0][kk], acc[1][0], 0, 0, 0);
            acc[1][1] = __builtin_amdgcn_mfma_f32_32x32x16_bf16(a1l, bfh[1][kk], acc[1][1], 0, 0, 0);
            acc[0][0] = __builtin_amdgcn_mfma_f32_32x32x16_bf16(a0h, bfl[0][kk], acc[0][0], 0, 0, 0);
            acc[0][1] = __builtin_amdgcn_mfma_f32_32x32x16_bf16(a0h, bfl[1][kk], acc[0][1], 0, 0, 0);
            acc[1][0] = __builtin_amdgcn_mfma_f32_32x32x16_bf16(a1h, bfl[0][kk], acc[1][0], 0, 0, 0);
            acc[1][1] = __builtin_amdgcn_mfma_f32_32x32x16_bf16(a1h, bfl[1][kk], acc[1][1], 0, 0, 0);
        }

#pragma unroll
        for (int mt = 0; mt < 2; ++mt)
#pragma unroll
            for (int r = 0; r < 16; ++r) {
                float t0 = fmaf(lr, zr[r], acc[mt][0][r]); t0 = fmaf(-li, zi[r], t0);
                float t1 = fmaf(li, zr[r], acc[mt][1][r]); t1 = fmaf(lr, zi[r], t1);
                zr[r] = t0; zi[r] = t1;
            }
        // no trailing barrier: next sub writes the other buffer
    }

#pragma unroll
    for (int r = 0; r < 16; ++r)
        E[(size_t)c * 4096 + crow(r, lane) * HH + ch] = make_float2(zr[r], zi[r]);
}

// ---------------------------------------------------------------------------
// Carry hierarchy: R9 structure; the 32-step expansion chains now run in f32
// (lambda^8 from exact f64 squaring rounded once; <=32-step f32 chain adds
// ~1e-5 abs error, negligible vs threshold). Super-prefix stays f64.
// ---------------------------------------------------------------------------
__global__ __launch_bounds__(256) void k_cseg(
    const float* __restrict__ lre, const float* __restrict__ lim,
    const float2* __restrict__ E, float2* __restrict__ Esup)
{
    int g = blockIdx.x * 256 + threadIdx.x;
    int chain = g & 4095, seg = g >> 12, ch = chain & 127;
    float lrf, lif; lam_f32(lre[ch], lim[ch], lrf, lif);
    double prd = (double)lrf, pid = (double)lif;
#pragma unroll
    for (int s = 0; s < 3; ++s) { double nr = prd*prd - pid*pid, ni = 2.0*prd*pid; prd = nr; pid = ni; } // lambda^8
    float pr = (float)prd, pi = (float)pid;
    float2 e[CPS];
#pragma unroll
    for (int j = 0; j < CPS; ++j)
        e[j] = E[((size_t)seg * CPS + j) * 4096 + chain];
    float sr = 0.f, si = 0.f;
#pragma unroll
    for (int j = 0; j < CPS; ++j) {
        float nr = fmaf(pr, sr, fmaf(-pi, si, e[j].x));
        float ni = fmaf(pi, sr, fmaf(pr, si, e[j].y));
        sr = nr; si = ni;
    }
    Esup[(size_t)seg * 4096 + chain] = make_float2(sr, si);
}

__global__ __launch_bounds__(256) void k_cexp2(
    const float* __restrict__ lre, const float* __restrict__ lim,
    const float2* __restrict__ x0p, const float2* __restrict__ Esup,
    const float2* __restrict__ E, float2* __restrict__ Carry)
{
    int g = blockIdx.x * 256 + threadIdx.x;
    int chain = g & 4095, seg = g >> 12, ch = chain & 127;
    float lrf, lif; lam_f32(lre[ch], lim[ch], lrf, lif);
    double p8r = (double)lrf, p8i = (double)lif;
#pragma unroll
    for (int s = 0; s < 3; ++s) { double nr = p8r*p8r - p8i*p8i, ni = 2.0*p8r*p8i; p8r = nr; p8i = ni; } // lambda^8
    double pr = p8r, pi = p8i;
#pragma unroll
    for (int s = 0; s < 5; ++s) { double nr = pr*pr - pi*pi, ni = 2.0*pr*pi; pr = nr; pi = ni; } // lambda^256
    // super-prefix in f64 (feeds 512-step-amplified carries)
    float2 es[SEGN - 1];
#pragma unroll
    for (int s = 0; s < SEGN - 1; ++s)
        es[s] = Esup[(size_t)s * 4096 + chain];
    float2 c0 = x0p[chain];
    double crd = (double)c0.x, cid = (double)c0.y;
#pragma unroll
    for (int s = 0; s < SEGN - 1; ++s) {
        if (s < seg) {
            double nr = pr * crd - pi * cid + (double)es[s].x;
            double ni = pi * crd + pr * cid + (double)es[s].y;
            crd = nr; cid = ni;
        }
    }
    // expansion within segment: f32 chain (<=32 dependent steps)
    float l8r = (float)p8r, l8i = (float)p8i;
    float cr = (float)crd, ci = (float)cid;
    float2 e[CPS];
#pragma unroll
    for (int j = 0; j < CPS; ++j)
        e[j] = E[((size_t)seg * CPS + j) * 4096 + chain];
#pragma unroll
    for (int j = 0; j < CPS; ++j) {
        Carry[((size_t)seg * CPS + j) * 4096 + chain] = make_float2(cr, ci);
        float nr = fmaf(l8r, cr, fmaf(-l8i, ci, e[j].x));
        float ni = fmaf(l8i, cr, fmaf(l8r, ci, e[j].y));
        cr = nr; ci = ni;
    }
}

// ---------------------------------------------------------------------------
// Pass 2: R2's measured-best kernel, verbatim (53.4 / 53.3 us; do not touch).
// LDS = 16384 (sU swz) + 65536 (sX swz) = 81920 B; (256,1); VGPR 256.
// ---------------------------------------------------------------------------
__global__ __launch_bounds__(256, 1) void k_pass2(
    const float* __restrict__ U,
    const unsigned short* __restrict__ Bph, const unsigned short* __restrict__ Bpl,
    const unsigned short* __restrict__ Wph, const unsigned short* __restrict__ Wpl,
    const float* __restrict__ lre, const float* __restrict__ lim,
    const float* __restrict__ bx2y,
    const float2* __restrict__ Carry, float* __restrict__ Y)
{
    __shared__ __align__(16) unsigned short sU[64 * 128];   // 16384 B, swizzled
    __shared__ __align__(16) unsigned short sX[64 * 512];   // 65536 B, swizzled

    const int tid = threadIdx.x, w = tid >> 6, lane = tid & 63;
    const int l31 = lane & 31, kh = lane >> 5;
    const int c = blockIdx.x;
    const int ch = w * 32 + l31;             // scan channel
    const int mtile = w & 1, ntile = w >> 1; // out-GEMM tile mapping

    float lr, li; lam_f32(lre[ch], lim[ch], lr, li);
    float ybias = bx2y[ntile * 32 + l31];

    bf16x8 bfh[2][4], bfl[2][4];
#pragma unroll
    for (int nt = 0; nt < 2; ++nt)
#pragma unroll
        for (int kk = 0; kk < 4; ++kk) {
            bfh[nt][kk] = ldfrag(&Bph[(size_t)(nt * HH + ch) * NUU + kk * 16 + kh * 8]);
            bfl[nt][kk] = ldfrag(&Bpl[(size_t)(nt * HH + ch) * NUU + kk * 16 + kh * 8]);
        }

    bf16x8 wfh[16], wfl[16];
#pragma unroll
    for (int kk = 0; kk < 16; ++kk) {
        wfh[kk] = ldfrag(&Wph[(size_t)(ntile * 32 + l31) * NHH + kk * 16 + kh * 8]);
        wfl[kk] = ldfrag(&Wpl[(size_t)(ntile * 32 + l31) * NHH + kk * 16 + kh * 8]);
    }

    float zr[16], zi[16];
#pragma unroll
    for (int r = 0; r < 16; ++r) {
        float2 v = Carry[(size_t)c * 4096 + crow(r, lane) * HH + ch];
        zr[r] = v.x; zi[r] = v.y;
    }

    const int srow = tid >> 2, sus = (tid & 3) * 16;
    const int sb = srow & 31, stoff = srow >> 5;
    const float* ubase = U + (size_t)sb * NUU + sus;

    float4 f0, f1, f2, f3;
    {
        const float4* sp = (const float4*)(ubase + (size_t)(c * LCH + stoff) * (NBB * NUU));
        f0 = sp[0]; f1 = sp[1]; f2 = sp[2]; f3 = sp[3];
    }

    for (int sub = 0; sub < 4; ++sub) {
        {   // convert + write sU (swizzled)
            bf16x8 h0, h1, l0, l1;
            CVT(f0.x, h0[0], l0[0]); CVT(f0.y, h0[1], l0[1]); CVT(f0.z, h0[2], l0[2]); CVT(f0.w, h0[3], l0[3]);
            CVT(f1.x, h0[4], l0[4]); CVT(f1.y, h0[5], l0[5]); CVT(f1.z, h0[6], l0[6]); CVT(f1.w, h0[7], l0[7]);
            CVT(f2.x, h1[0], l1[0]); CVT(f2.y, h1[1], l1[1]); CVT(f2.z, h1[2], l1[2]); CVT(f2.w, h1[3], l1[3]);
            CVT(f3.x, h1[4], l1[4]); CVT(f3.y, h1[5], l1[5]); CVT(f3.z, h1[6], l1[6]); CVT(f3.w, h1[7], l1[7]);
            *(bf16x8*)&sU[swzU(srow, sus)]          = h0;
            *(bf16x8*)&sU[swzU(srow, sus + 8)]      = h1;
            *(bf16x8*)&sU[swzU(srow, 64 + sus)]     = l0;
            *(bf16x8*)&sU[swzU(srow, 64 + sus + 8)] = l1;
        }

        if (sub > 0) {  // out-GEMM for sub-1 (reads sX written before last barrier)
            f32x16 ya0, ya1, ya2;
#pragma unroll
            for (int r = 0; r < 16; ++r) { ya0[r] = 0.f; ya1[r] = 0.f; ya2[r] = 0.f; }
#pragma unroll
            for (int kk = 0; kk < 16; ++kk) {
                bf16x8 xah = ldfrag(&sX[swzX(mtile * 32 + l31, kk * 16 + kh * 8)]);
                bf16x8 xal = ldfrag(&sX[swzX(mtile * 32 + l31, 256 + kk * 16 + kh * 8)]);
                ya0 = __builtin_amdgcn_mfma_f32_32x32x16_bf16(xah, wfh[kk], ya0, 0, 0, 0);
                ya1 = __builtin_amdgcn_mfma_f32_32x32x16_bf16(xal, wfh[kk], ya1, 0, 0, 0);
                ya2 = __builtin_amdgcn_mfma_f32_32x32x16_bf16(xah, wfl[kk], ya2, 0, 0, 0);
            }
            int t = c * LCH + (sub - 1) * 2 + mtile;
#pragma unroll
            for (int r = 0; r < 16; ++r)
                Y[((size_t)t * NBB + crow(r, lane)) * NYY + ntile * 32 + l31] =
                    (ya0[r] + ya1[r]) + ya2[r] + ybias;
        }
        __syncthreads();

        if (sub < 3) {   // prefetch next sub; lands under the MFMA phase
            const float4* sp = (const float4*)(ubase + (size_t)(c * LCH + (sub + 1) * 2 + stoff) * (NBB * NUU));
            f0 = sp[0]; f1 = sp[1]; f2 = sp[2]; f3 = sp[3];
        }

        // Bu MFMA (split 3-term)
        f32x16 acc[2][2];
#pragma unroll
        for (int mt = 0; mt < 2; ++mt)
#pragma unroll
            for (int nt = 0; nt < 2; ++nt)
#pragma unroll
                for (int r = 0; r < 16; ++r) acc[mt][nt][r] = 0.f;

#pragma unroll
        for (int kk = 0; kk < 4; ++kk) {
            bf16x8 a0h = ldfrag(&sU[swzU(l31,      kk * 16 + kh * 8)]);
            bf16x8 a1h = ldfrag(&sU[swzU(32 + l31, kk * 16 + kh * 8)]);
            bf16x8 a0l = ldfrag(&sU[swzU(l31,      64 + kk * 16 + kh * 8)]);
            bf16x8 a1l = ldfrag(&sU[swzU(32 + l31, 64 + kk * 16 + kh * 8)]);
            acc[0][0] = __builtin_amdgcn_mfma_f32_32x32x16_bf16(a0h, bfh[0][kk], acc[0][0], 0, 0, 0);
            acc[0][1] = __builtin_amdgcn_mfma_f32_32x32x16_bf16(a0h, bfh[1][kk], acc[0][1], 0, 0, 0);
            acc[1][0] = __builtin_amdgcn_mfma_f32_32x32x16_bf16(a1h, bfh[0][kk], acc[1][0], 0, 0, 0);
            acc[1][1] = __builtin_amdgcn_mfma_f32_32x32x16_bf16(a1h, bfh[1][kk], acc[1][1], 0, 0, 0);
            acc[0][0] = __builtin_amdgcn_mfma_f32_32x32x16_bf16(a0l, bfh[0][kk], acc[0][0], 0, 0, 0);
            acc[0][1] = __builtin_amdgcn_mfma_f32_32x32x16_bf16(a0l, bfh[1][kk], acc[0][1], 0, 0, 0);
            acc[1][0] = __builtin_amdgcn_mfma_f32_32x32x16_bf16(a1l, bfh[0][kk], acc[1][0], 0, 0, 0);
            acc[1][1] = __builtin_amdgcn_mfma_f32_32x32x16_bf16(a1l, bfh[1][kk], acc[1][1], 0, 0, 0);
            acc[0][0] = __builtin_amdgcn_mfma_f32_32x32x16_bf16(a0h, bfl[0][kk], acc[0][0], 0, 0, 0);
            acc[0][1] = __builtin_amdgcn_mfma_f32_32x32x16_bf16(a0h, bfl[1][kk], acc[0][1], 0, 0, 0);
            acc[1][0] = __builtin_amdgcn_mfma_f32_32x32x16_bf16(a1h, bfl[0][kk], acc[1][0], 0, 0, 0);
            acc[1][1] = __builtin_amdgcn_mfma_f32_32x32x16_bf16(a1h, bfl[1][kk], acc[1][1], 0, 0, 0);
        }

        // Scan + split hi/lo dump (two b32 per (mt,r)), swizzled
#pragma unroll
        for (int mt = 0; mt < 2; ++mt)
#pragma unroll
            for (int r = 0; r < 16; ++r) {
                float t0 = fmaf(lr, zr[r], acc[mt][0][r]); t0 = fmaf(-li, zi[r], t0);
                float t1 = fmaf(li, zr[r], acc[mt][1][r]); t1 = fmaf(lr, zi[r], t1);
                zr[r] = t0; zi[r] = t1;
                bf16x2 hv, lv;
                { __bf16 _h = (__bf16)t0; hv[0] = _h; lv[0] = (__bf16)(t0 - (float)_h); }
                { __bf16 _h = (__bf16)t1; hv[1] = _h; lv[1] = (__bf16)(t1 - (float)_h); }
                int row = mt * 32 + crow(r, lane);
                *(bf16x2*)&sX[swzX(row, w * 64 + 2 * l31)]       = hv;
                *(bf16x2*)&sX[swzX(row, 256 + w * 64 + 2 * l31)] = lv;
            }
        __syncthreads();
    }

    // Drain: out-GEMM for sub=3
    {
        f32x16 ya0, ya1, ya2;
#pragma unroll
        for (int r = 0; r < 16; ++r) { ya0[r] = 0.f; ya1[r] = 0.f; ya2[r] = 0.f; }
#pragma unroll
        for (int kk = 0; kk < 16; ++kk) {
            bf16x8 xah = ldfrag(&sX[swzX(mtile * 32 + l31, kk * 16 + kh * 8)]);
            bf16x8 xal = ldfrag(&sX[swzX(mtile * 32 + l31, 256 + kk * 16 + kh * 8)]);
            ya0 = __builtin_amdgcn_mfma_f32_32x32x16_bf16(xah, wfh[kk], ya0, 0, 0, 0);
            ya1 = __builtin_amdgcn_mfma_f32_32x32x16_bf16(xal, wfh[kk], ya1, 0, 0, 0);
            ya2 = __builtin_amdgcn_mfma_f32_32x32x16_bf16(xah, wfl[kk], ya2, 0, 0, 0);
        }
        int t = c * LCH + 3 * 2 + mtile;
#pragma unroll
        for (int r = 0; r < 16; ++r)
            Y[((size_t)t * NBB + crow(r, lane)) * NYY + ntile * 32 + l31] =
                (ya0[r] + ya1[r]) + ya2[r] + ybias;
    }
}

// ---------------------------------------------------------------------------
extern "C" void kernel_launch(void* const* d_in, const int* in_sizes, int n_in,
                              void* d_out, int out_size, void* d_ws, size_t ws_size,
                              hipStream_t stream) {
    const float* y0    = (const float*)d_in[0];
    const float* U     = (const float*)d_in[1];
    const float* lre   = (const float*)d_in[2];
    const float* lim   = (const float*)d_in[3];
    const float* B     = (const float*)d_in[4];
    const float* W_y2x = (const float*)d_in[5];
    const float* b_y2x = (const float*)d_in[6];
    const float* W_x2y = (const float*)d_in[7];
    const float* b_x2y = (const float*)d_in[8];
    float* Y = (float*)d_out;

    char* p = (char*)d_ws;
    float2* E        = (float2*)p; p += (size_t)CCH * 4096 * sizeof(float2);   // 16.8 MB
    float2* Carry    = (float2*)p; p += (size_t)CCH * 4096 * sizeof(float2);   // 16.8 MB
    float2* Esup     = (float2*)p; p += (size_t)SEGN * 4096 * sizeof(float2);  // 512 KB
    float2* x0p      = (float2*)p; p += (size_t)4096 * sizeof(float2);         // 32 KB
    unsigned short* Bph = (unsigned short*)p; p += 16384 * sizeof(unsigned short);
    unsigned short* Bpl = (unsigned short*)p; p += 16384 * sizeof(unsigned short);
    unsigned short* Wph = (unsigned short*)p; p += 16384 * sizeof(unsigned short);
    unsigned short* Wpl = (unsigned short*)p; p += 16384 * sizeof(unsigned short);

    k_prep <<<dim3(96),  dim3(256), 0, stream>>>(B, W_x2y, y0, W_y2x, b_y2x, Bph, Bpl, Wph, Wpl, x0p);
    k_pass1<<<dim3(CCH), dim3(256), 0, stream>>>(U, Bph, Bpl, lre, lim, E);
    k_cseg <<<dim3(256), dim3(256), 0, stream>>>(lre, lim, E, Esup);
    k_cexp2<<<dim3(256), dim3(256), 0, stream>>>(lre, lim, x0p, Esup, E, Carry);
    k_pass2<<<dim3(CCH), dim3(256), 0, stream>>>(U, Bph, Bpl, Wph, Wpl, lre, lim, b_x2y, Carry, Y);
}